// Round 14
// baseline (324.030 us; speedup 1.0000x reference)
//
#include <hip/hip_runtime.h>
#include <hip/hip_bf16.h>
#include <cstddef>

#define B_    128
#define D_    2048
#define C_    16522
#define BETA_INV 20.0f      // 1/0.05
#define LSTRIDE 16528       // padded logits row stride (floats)

#define NTILES 1033         // ceil(C/16)
#define ROWSTRIDE 1040      // 1024 B (256 fp32) + 16 B pad -> conflict-free frag reads
#define CHUNK_B   (16 * ROWSTRIDE)   // 16640 B per chunk buffer

typedef __bf16 bf16;
typedef bf16  bf16x8 __attribute__((ext_vector_type(8)));
typedef bf16  bf16x4 __attribute__((ext_vector_type(4)));
typedef float f32x4  __attribute__((ext_vector_type(4)));

// ws layout (bytes):
//   logits : [0, 8462336)                128*16528*4
//   A_pack : [8462336, 8986624)          128*2048*2  bf16 fragment-ordered
#define WS_APACK_OFF 8462336

// ---------------------------------------------------------------------------
// pack_a: inputs [128,2048] fp32 -> bf16 in MFMA A-fragment order.
// Also zeroes the loss accumulator (stream-ordered before tail's atomics).
// ---------------------------------------------------------------------------
__global__ __launch_bounds__(256) void pack_a(const float* __restrict__ inp,
                                              bf16* __restrict__ ap,
                                              float* __restrict__ out) {
  const int tid  = blockIdx.x * 256 + threadIdx.x;   // 0..32767
  if (tid == 0) out[0] = 0.f;
  const int lane = tid & 63;
  const int ks   = (tid >> 6) & 63;
  const int mt   = tid >> 12;
  const int row  = mt * 16 + (lane & 15);
  const int col  = ks * 32 + (lane >> 4) * 8;
  const f32x4 v0 = *(const f32x4*)(inp + row * D_ + col);
  const f32x4 v1 = *(const f32x4*)(inp + row * D_ + col + 4);
  bf16x8 b;
  b[0] = (bf16)v0[0]; b[1] = (bf16)v0[1]; b[2] = (bf16)v0[2]; b[3] = (bf16)v0[3];
  b[4] = (bf16)v1[0]; b[5] = (bf16)v1[1]; b[6] = (bf16)v1[2]; b[7] = (bf16)v1[3];
  ((bf16x8*)ap)[tid] = b;
}

// ---------------------------------------------------------------------------
// gemm, round 14: global_load_lds DMA staging (the one untried mechanism).
// Rounds 5-13 bracket (94-116us) all used REGISTER staging: global->VGPR->
// cvt->ds_write. That chain is why every schedule convoyed — loads can't
// stream during compute without VGPR carry (r9/r12 showed its cost), and
// each barrier drains a load->reg->LDS dependency. global_load_lds removes
// the VGPR leg entirely: DMA(c+1) streams into the idle LDS buffer DURING
// the MFMA phase of chunk c, at zero register cost; the barrier drains a
// DMA that already had a full compute phase of slack.
//  - em staged as FP32 (DMA can't convert); fp32->bf16 cvt moves into the
//    k-loop (~8 cvt per MFMA step; k-phase is small).
//  - BK=256 floats/chunk: 16 rows x (1024+16 pad) = 16.6 KB; 2 buffers =
//    33 KB -> 4 blocks/CU (32 waves/CU, was 2 blocks).
//  - 16B row pad => frag-read bank slots s=(4*ml+8*quad)%32 tile all 32
//    banks at the 1KB floor: conflict-free, no XOR swizzle needed.
//  - per chunk: DMA(c+1) [2 wave-instrs, per-lane global src, wave-uniform
//    LDS dest, linear per m104] -> copyout(c) LDS->out_em (stores get the
//    whole compute phase of slack) -> 8 MFMA k-steps -> __syncthreads.
// ---------------------------------------------------------------------------
__global__ __launch_bounds__(512, 8) void gemm_logits(
    const bf16*  __restrict__ ap,
    const float* __restrict__ em,
    float*       __restrict__ logits,
    float*       __restrict__ out_em)
{
  __shared__ char sB[2][CHUNK_B];      // 33,280 B total, fp32 tiles

  const int t    = threadIdx.x;
  const int lane = t & 63;
  const int w    = t >> 6;             // wave id 0..7 == m-tile index
  const int ml   = lane & 15;
  const int quad = lane >> 4;
  const int n0   = blockIdx.x * 16;
  const int r    = n0 + ml;

  // DMA mapping: wave w owns tile rows {2w, 2w+1}; each row = one 1KB
  // wave-instr (lane supplies 16B at em_row + c*256 + lane*4 floats).
  const int r0  = 2 * w, r1 = 2 * w + 1;
  const int gd0 = (n0 + r0 < C_) ? n0 + r0 : C_ - 1;
  const int gd1 = (n0 + r1 < C_) ? n0 + r1 : C_ - 1;
  const float* g0 = em + (size_t)gd0 * D_ + lane * 4;
  const float* g1 = em + (size_t)gd1 * D_ + lane * 4;

  // copyout mapping: thread t handles tile row tr = t>>5, 32B at slot u.
  const int tr = t >> 5, u = t & 31;
  const int grc = n0 + tr;

  // prologue: DMA chunk 0 into buffer 0
  __builtin_amdgcn_global_load_lds(
      (const __attribute__((address_space(1))) void*)g0,
      (__attribute__((address_space(3))) void*)&sB[0][r0 * ROWSTRIDE], 16, 0, 0);
  __builtin_amdgcn_global_load_lds(
      (const __attribute__((address_space(1))) void*)g1,
      (__attribute__((address_space(3))) void*)&sB[0][r1 * ROWSTRIDE], 16, 0, 0);
  __syncthreads();

  f32x4 acc = {};
  const bf16x8* apc = (const bf16x8*)ap + (size_t)(w * 64) * 64 + lane;
  const int fbyte = ml * ROWSTRIDE + quad * 32;   // frag base within chunk

  #pragma unroll
  for (int c = 0; c < 8; ++c) {
    // 1) issue next chunk's DMA (streams during this chunk's compute)
    if (c < 7) {
      char* nb = sB[(c + 1) & 1];
      __builtin_amdgcn_global_load_lds(
          (const __attribute__((address_space(1))) void*)(g0 + (c + 1) * 256),
          (__attribute__((address_space(3))) void*)&nb[r0 * ROWSTRIDE], 16, 0, 0);
      __builtin_amdgcn_global_load_lds(
          (const __attribute__((address_space(1))) void*)(g1 + (c + 1) * 256),
          (__attribute__((address_space(3))) void*)&nb[r1 * ROWSTRIDE], 16, 0, 0);
    }

    const char* sb = sB[c & 1];

    // 2) copyout chunk c: LDS (fp32, exact) -> out_em; stores drain under
    //    the following compute phase.
    if (grc < C_) {
      float* drow = out_em + (size_t)grc * D_ + c * 256;
      const char* srow = sb + tr * ROWSTRIDE + u * 32;
      *(f32x4*)(drow + u * 8)     = *(const f32x4*)(srow);
      *(f32x4*)(drow + u * 8 + 4) = *(const f32x4*)(srow + 16);
    }

    // 3) compute chunk c: 8 MFMA k-steps; B-frag = fp32x8 from LDS -> bf16
    #pragma unroll
    for (int ksl = 0; ksl < 8; ++ksl) {
      const f32x4 a0 = *(const f32x4*)(sb + fbyte + ksl * 128);
      const f32x4 a1 = *(const f32x4*)(sb + fbyte + ksl * 128 + 16);
      bf16x8 bv;
      bv[0] = (bf16)a0[0]; bv[1] = (bf16)a0[1]; bv[2] = (bf16)a0[2]; bv[3] = (bf16)a0[3];
      bv[4] = (bf16)a1[0]; bv[5] = (bf16)a1[1]; bv[6] = (bf16)a1[2]; bv[7] = (bf16)a1[3];
      acc = __builtin_amdgcn_mfma_f32_16x16x32_bf16(
          apc[(size_t)(c * 8 + ksl) * 64], bv, acc, 0, 0, 0);
    }

    __syncthreads();   // drains DMA(c+1) (one phase of slack) + stores(c)
  }

  if (r < C_) {
    #pragma unroll
    for (int reg = 0; reg < 4; ++reg) {
      const int row = w * 16 + quad * 4 + reg;
      logits[row * LSTRIDE + r] = acc[reg] * BETA_INV;
    }
  }
}

// ---------------------------------------------------------------------------
// tail: fused row_loss (blocks 0..127, one block per sample row, full-row
// scan) and em_update (blocks 128..255). Branch is block-uniform.
// ---------------------------------------------------------------------------
__global__ __launch_bounds__(256) void tail(
    const float* __restrict__ logits,
    const int*   __restrict__ label,
    const float* __restrict__ inp,
    const float* __restrict__ em,
    const int*   __restrict__ epoch,
    float*       __restrict__ out,
    float*       __restrict__ out_em)
{
  __shared__ float rm[256], rs[256];
  __shared__ float cv[1536];
  __shared__ int   ci[1536];
  __shared__ float sly;
  __shared__ int   lbl[B_];
  __shared__ float red[4];

  const int t = threadIdx.x;

  if (blockIdx.x < B_) {
    // ---------------- row_loss: full row b, online lse + top-6 ----------
    const int b = blockIdx.x;
    const float* row = logits + b * LSTRIDE;
    const int y = label[b];

    float m = -INFINITY, s = 0.f, ly = -INFINITY;
    float tv[6]; int ti[6];
    #pragma unroll
    for (int q = 0; q < 6; ++q) { tv[q] = -INFINITY; ti[q] = -1; }

    for (int i = t; i < C_; i += 256) {
      const float v = row[i];
      if (v > m) { s = s * __expf(m - v) + 1.f; m = v; }
      else       { s += __expf(v - m); }
      if (i == y) ly = v;
      if (v > tv[5]) {
        tv[5] = v; ti[5] = i;
        #pragma unroll
        for (int q = 5; q > 0; --q)
          if (tv[q] > tv[q - 1]) {
            const float fv = tv[q]; tv[q] = tv[q - 1]; tv[q - 1] = fv;
            const int   fi = ti[q]; ti[q] = ti[q - 1]; ti[q - 1] = fi;
          }
      }
    }

    rm[t] = m; rs[t] = s;
    #pragma unroll
    for (int q = 0; q < 6; ++q) { cv[t * 6 + q] = tv[q]; ci[t * 6 + q] = ti[q]; }
    if (t == 0) sly = -INFINITY;
    __syncthreads();
    if (ly != -INFINITY) sly = ly;

    for (int off = 128; off >= 1; off >>= 1) {
      if (t < off) {
        const float m2 = rm[t + off], s2 = rs[t + off];
        const float M = fmaxf(rm[t], m2);
        rs[t] = rs[t] * __expf(rm[t] - M) + s2 * __expf(m2 - M);
        rm[t] = M;
      }
      __syncthreads();
    }

    if (t < 64) {   // wave 0: top-6 of 1536 candidates
      float otv[6]; int oti[6];
      for (int rr = 0; rr < 6; ++rr) {
        float bv = -INFINITY; int bi = -1, bs = -1;
        for (int uu = 0; uu < 24; ++uu) {
          const int slot = t * 24 + uu;
          const float v = cv[slot];
          if (v > bv) { bv = v; bi = ci[slot]; bs = slot; }
        }
        #pragma unroll
        for (int off = 32; off >= 1; off >>= 1) {
          const float ov = __shfl_down(bv, off);
          const int   oi = __shfl_down(bi, off);
          const int   os = __shfl_down(bs, off);
          if (ov > bv) { bv = ov; bi = oi; bs = os; }
        }
        bv = __shfl(bv, 0); bi = __shfl(bi, 0); bs = __shfl(bs, 0);
        if (bs >= t * 24 && bs < (t + 1) * 24) cv[bs] = -INFINITY;
        otv[rr] = bv; oti[rr] = bi;
      }
      if (t == 0) {
        const float lse = rm[0] + logf(rs[0]);
        float stop = 0.f; int intop = 0;
        #pragma unroll
        for (int q = 0; q < 6; ++q) {
          stop += otv[q];
          if (oti[q] == y) intop = 1;
        }
        const float lyv = sly;
        const float loss = intop ? (13.f * lse - lyv - 2.f * stop)
                                 : (15.f * lse - 3.f * lyv - 2.f * stop);
        atomicAdd(out, loss * (1.0f / 128.0f));
      }
    }
  } else {
    // ---------------- em_update: sample i = blockIdx.x - 128 ------------
    if (t < B_) lbl[t] = label[t];
    __syncthreads();

    const int i = blockIdx.x - B_;
    const int y = lbl[i];
    for (int j = 0; j < i; ++j)
      if (lbl[j] == y) return;          // uniform: all threads agree

    const float alpha = 0.01f * (float)epoch[0];
    const int lane = t & 63, wave = t >> 6;

    float rreg[8];
    #pragma unroll
    for (int uu = 0; uu < 8; ++uu) rreg[uu] = em[(size_t)y * D_ + t + uu * 256];

    for (int j = i; j < B_; ++j) {
      if (lbl[j] != y) continue;        // uniform branch
      const float* x = inp + j * D_;
      float ss = 0.f;
      #pragma unroll
      for (int uu = 0; uu < 8; ++uu) {
        rreg[uu] = alpha * rreg[uu] + (1.f - alpha) * x[t + uu * 256];
        ss += rreg[uu] * rreg[uu];
      }
      #pragma unroll
      for (int off = 32; off >= 1; off >>= 1) ss += __shfl_down(ss, off);
      if (lane == 0) red[wave] = ss;
      __syncthreads();
      const float inv = 1.f / sqrtf(red[0] + red[1] + red[2] + red[3]);
      #pragma unroll
      for (int uu = 0; uu < 8; ++uu) rreg[uu] *= inv;
      __syncthreads();                  // red[] reused next chain step
    }

    #pragma unroll
    for (int uu = 0; uu < 8; ++uu) out_em[(size_t)y * D_ + t + uu * 256] = rreg[uu];
  }
}

// ---------------------------------------------------------------------------
extern "C" void kernel_launch(void* const* d_in, const int* in_sizes, int n_in,
                              void* d_out, int out_size, void* d_ws, size_t ws_size,
                              hipStream_t stream) {
  const float* inp   = (const float*)d_in[0];
  const int*   label = (const int*)d_in[1];
  const float* em    = (const float*)d_in[2];
  const int*   epoch = (const int*)d_in[3];

  float* out    = (float*)d_out;
  float* out_em = out + 1;
  float* logits = (float*)d_ws;
  bf16*  apack  = (bf16*)((char*)d_ws + WS_APACK_OFF);

  pack_a      <<<dim3(128),    dim3(256), 0, stream>>>(inp, apack, out);
  gemm_logits <<<dim3(NTILES), dim3(512), 0, stream>>>(apack, em, logits, out_em);
  tail        <<<dim3(2 * B_), dim3(256), 0, stream>>>(logits, label, inp, em,
                                                       epoch, out, out_em);
}

// Round 15
// 305.337 us; speedup vs baseline: 1.0612x; 1.0612x over previous
//
#include <hip/hip_runtime.h>
#include <hip/hip_bf16.h>
#include <cstddef>

#define B_    128
#define D_    2048
#define C_    16522
#define BETA_INV 20.0f      // 1/0.05
#define LSTRIDE 16528       // padded logits row stride (floats)

#define NTILES 1033         // ceil(C/16)

typedef __bf16 bf16;
typedef bf16  bf16x8 __attribute__((ext_vector_type(8)));
typedef bf16  bf16x4 __attribute__((ext_vector_type(4)));
typedef float f32x4  __attribute__((ext_vector_type(4)));

// ws layout (bytes):
//   logits : [0, 8462336)                128*16528*4
//   A_pack : [8462336, 8986624)          128*2048*2  bf16 fragment-ordered
#define WS_APACK_OFF 8462336

// ---------------------------------------------------------------------------
// pack_a: inputs [128,2048] fp32 -> bf16 in MFMA A-fragment order.
// Also zeroes the loss accumulator (stream-ordered before tail's atomics).
// ---------------------------------------------------------------------------
__global__ __launch_bounds__(256) void pack_a(const float* __restrict__ inp,
                                              bf16* __restrict__ ap,
                                              float* __restrict__ out) {
  const int tid  = blockIdx.x * 256 + threadIdx.x;   // 0..32767
  if (tid == 0) out[0] = 0.f;
  const int lane = tid & 63;
  const int ks   = (tid >> 6) & 63;
  const int mt   = tid >> 12;
  const int row  = mt * 16 + (lane & 15);
  const int col  = ks * 32 + (lane >> 4) * 8;
  const f32x4 v0 = *(const f32x4*)(inp + row * D_ + col);
  const f32x4 v1 = *(const f32x4*)(inp + row * D_ + col + 4);
  bf16x8 b;
  b[0] = (bf16)v0[0]; b[1] = (bf16)v0[1]; b[2] = (bf16)v0[2]; b[3] = (bf16)v0[3];
  b[4] = (bf16)v1[0]; b[5] = (bf16)v1[1]; b[6] = (bf16)v1[2]; b[7] = (bf16)v1[3];
  ((bf16x8*)ap)[tid] = b;
}

static __device__ __forceinline__ bf16x4 cvt4(const f32x4 v) {
  bf16x4 h;
  h[0] = (bf16)v[0]; h[1] = (bf16)v[1]; h[2] = (bf16)v[2]; h[3] = (bf16)v[3];
  return h;
}

// ---------------------------------------------------------------------------
// gemm, round 15: round-6 structure with a NO-VMCNT-DRAIN barrier.
// Round-14 post-mortem: per-chunk __syncthreads drained copyout stores with
// zero slack 8x/block (108us); round 6's single __syncthreads does the same
// once: its vmcnt(0) waits for the out_em store acks issued immediately
// before it. Fix (T4 principle, one line): s_waitcnt lgkmcnt(0) + raw
// s_barrier — orders the LDS writes for the k-loop but lets the 128KB of
// out_em stores retire lazily under the k-loop (cached stores ack at L2;
// they are older than the k-loop's A-frag loads, so the compiler's first
// A-load wait retires them at ~L2-ack cost, overlapped with MFMA).
// Correctness: ds_writes ordered by lgkmcnt(0); staging loads consumed
// before ds_write (data dep); out_em is only read by the next dispatch
// (stream-ordered; dispatch-end flushes stores).
// Also: all 16 staging loads issued as ONE burst (deeper MLP; round-9
// showed 16-burst is fine when stores are NOT deferred/register-carried).
// Everything else round-6 verbatim. Pre-commit: null => ROOFLINE.
// ---------------------------------------------------------------------------
__global__ __launch_bounds__(512, 4) void gemm_logits(
    const bf16*  __restrict__ ap,
    const float* __restrict__ em,
    float*       __restrict__ logits,
    float*       __restrict__ out_em)
{
  __shared__ bf16 sB[16 * 2048];       // 64 KB, swizzled layout

  const int t    = threadIdx.x;
  const int lane = t & 63;
  const int w    = t >> 6;             // wave id 0..7 == m-tile index
  const int ml   = lane & 15;
  const int quad = lane >> 4;
  const int n0   = blockIdx.x * 16;
  const int r    = n0 + ml;
  const bool valid = r < C_;

  // ---- staging: wave w owns rows w and w+8; ONE 16-load burst ----------
  const int row0 = w, row1 = w + 8;
  const int gr0 = (n0 + row0 < C_) ? (n0 + row0) : (C_ - 1);
  const int gr1 = (n0 + row1 < C_) ? (n0 + row1) : (C_ - 1);
  const f32x4* s0 = (const f32x4*)(em + (size_t)gr0 * D_);
  const f32x4* s1 = (const f32x4*)(em + (size_t)gr1 * D_);

  f32x4 g[16];
  #pragma unroll
  for (int i = 0; i < 8; ++i) g[i]     = s0[lane + i * 64];
  #pragma unroll
  for (int i = 0; i < 8; ++i) g[8 + i] = s1[lane + i * 64];

  const int swz = (w & 7) << 4;        // same key for rows w and w+8
  #pragma unroll
  for (int i = 0; i < 8; ++i) {
    const int byte0 = (row0 << 12) + (lane << 3) + (i << 9);
    *(bf16x4*)((char*)sB + (byte0 ^ swz)) = cvt4(g[i]);
  }
  #pragma unroll
  for (int i = 0; i < 8; ++i) {
    const int byte1 = (row1 << 12) + (lane << 3) + (i << 9);
    *(bf16x4*)((char*)sB + (byte1 ^ swz)) = cvt4(g[8 + i]);
  }
  // copy-through stores (issued here; NOT drained by the barrier below)
  if (n0 + row0 < C_) {
    f32x4* d0 = (f32x4*)(out_em + (size_t)(n0 + row0) * D_);
    #pragma unroll
    for (int i = 0; i < 8; ++i) d0[lane + i * 64] = g[i];
  }
  if (n0 + row1 < C_) {
    f32x4* d1 = (f32x4*)(out_em + (size_t)(n0 + row1) * D_);
    #pragma unroll
    for (int i = 0; i < 8; ++i) d1[lane + i * 64] = g[8 + i];
  }

  // no-vmcnt-drain barrier: LDS writes ordered, stores drain lazily
  asm volatile("s_waitcnt lgkmcnt(0)" ::: "memory");
  __builtin_amdgcn_s_barrier();
  __builtin_amdgcn_sched_barrier(0);

  // ---- k-loop: 64 MFMA steps, B from LDS, A-frags from L2-hot A-pack ---
  f32x4 acc = {};
  const bf16x8* apc = (const bf16x8*)ap + (size_t)(w * 64) * 64 + lane;
  const char* sb = (const char*)sB;
  const int rbase = (ml << 12) + (quad << 4);   // ml*4096 + quad*16
  const int rswz  = (ml & 7) << 4;
  #pragma unroll 16
  for (int ks = 0; ks < 64; ++ks) {
    const bf16x8 bfrag = *(const bf16x8*)(sb + ((rbase + (ks << 6)) ^ rswz));
    acc = __builtin_amdgcn_mfma_f32_16x16x32_bf16(apc[(size_t)ks * 64], bfrag,
                                                  acc, 0, 0, 0);
  }

  if (valid) {
    #pragma unroll
    for (int reg = 0; reg < 4; ++reg) {
      const int row = w * 16 + quad * 4 + reg;
      logits[row * LSTRIDE + r] = acc[reg] * BETA_INV;
    }
  }
}

// ---------------------------------------------------------------------------
// tail: fused row_loss (blocks 0..127, one block per sample row, full-row
// scan) and em_update (blocks 128..255). Branch is block-uniform.
// ---------------------------------------------------------------------------
__global__ __launch_bounds__(256) void tail(
    const float* __restrict__ logits,
    const int*   __restrict__ label,
    const float* __restrict__ inp,
    const float* __restrict__ em,
    const int*   __restrict__ epoch,
    float*       __restrict__ out,
    float*       __restrict__ out_em)
{
  __shared__ float rm[256], rs[256];
  __shared__ float cv[1536];
  __shared__ int   ci[1536];
  __shared__ float sly;
  __shared__ int   lbl[B_];
  __shared__ float red[4];

  const int t = threadIdx.x;

  if (blockIdx.x < B_) {
    // ---------------- row_loss: full row b, online lse + top-6 ----------
    const int b = blockIdx.x;
    const float* row = logits + b * LSTRIDE;
    const int y = label[b];

    float m = -INFINITY, s = 0.f, ly = -INFINITY;
    float tv[6]; int ti[6];
    #pragma unroll
    for (int q = 0; q < 6; ++q) { tv[q] = -INFINITY; ti[q] = -1; }

    for (int i = t; i < C_; i += 256) {
      const float v = row[i];
      if (v > m) { s = s * __expf(m - v) + 1.f; m = v; }
      else       { s += __expf(v - m); }
      if (i == y) ly = v;
      if (v > tv[5]) {
        tv[5] = v; ti[5] = i;
        #pragma unroll
        for (int q = 5; q > 0; --q)
          if (tv[q] > tv[q - 1]) {
            const float fv = tv[q]; tv[q] = tv[q - 1]; tv[q - 1] = fv;
            const int   fi = ti[q]; ti[q] = ti[q - 1]; ti[q - 1] = fi;
          }
      }
    }

    rm[t] = m; rs[t] = s;
    #pragma unroll
    for (int q = 0; q < 6; ++q) { cv[t * 6 + q] = tv[q]; ci[t * 6 + q] = ti[q]; }
    if (t == 0) sly = -INFINITY;
    __syncthreads();
    if (ly != -INFINITY) sly = ly;

    for (int off = 128; off >= 1; off >>= 1) {
      if (t < off) {
        const float m2 = rm[t + off], s2 = rs[t + off];
        const float M = fmaxf(rm[t], m2);
        rs[t] = rs[t] * __expf(rm[t] - M) + s2 * __expf(m2 - M);
        rm[t] = M;
      }
      __syncthreads();
    }

    if (t < 64) {   // wave 0: top-6 of 1536 candidates
      float otv[6]; int oti[6];
      for (int rr = 0; rr < 6; ++rr) {
        float bv = -INFINITY; int bi = -1, bs = -1;
        for (int u = 0; u < 24; ++u) {
          const int slot = t * 24 + u;
          const float v = cv[slot];
          if (v > bv) { bv = v; bi = ci[slot]; bs = slot; }
        }
        #pragma unroll
        for (int off = 32; off >= 1; off >>= 1) {
          const float ov = __shfl_down(bv, off);
          const int   oi = __shfl_down(bi, off);
          const int   os = __shfl_down(bs, off);
          if (ov > bv) { bv = ov; bi = oi; bs = os; }
        }
        bv = __shfl(bv, 0); bi = __shfl(bi, 0); bs = __shfl(bs, 0);
        if (bs >= t * 24 && bs < (t + 1) * 24) cv[bs] = -INFINITY;
        otv[rr] = bv; oti[rr] = bi;
      }
      if (t == 0) {
        const float lse = rm[0] + logf(rs[0]);
        float stop = 0.f; int intop = 0;
        #pragma unroll
        for (int q = 0; q < 6; ++q) {
          stop += otv[q];
          if (oti[q] == y) intop = 1;
        }
        const float lyv = sly;
        const float loss = intop ? (13.f * lse - lyv - 2.f * stop)
                                 : (15.f * lse - 3.f * lyv - 2.f * stop);
        atomicAdd(out, loss * (1.0f / 128.0f));
      }
    }
  } else {
    // ---------------- em_update: sample i = blockIdx.x - 128 ------------
    if (t < B_) lbl[t] = label[t];
    __syncthreads();

    const int i = blockIdx.x - B_;
    const int y = lbl[i];
    for (int j = 0; j < i; ++j)
      if (lbl[j] == y) return;          // uniform: all threads agree

    const float alpha = 0.01f * (float)epoch[0];
    const int lane = t & 63, wave = t >> 6;

    float rreg[8];
    #pragma unroll
    for (int u = 0; u < 8; ++u) rreg[u] = em[(size_t)y * D_ + t + u * 256];

    for (int j = i; j < B_; ++j) {
      if (lbl[j] != y) continue;        // uniform branch
      const float* x = inp + j * D_;
      float ss = 0.f;
      #pragma unroll
      for (int u = 0; u < 8; ++u) {
        rreg[u] = alpha * rreg[u] + (1.f - alpha) * x[t + u * 256];
        ss += rreg[u] * rreg[u];
      }
      #pragma unroll
      for (int off = 32; off >= 1; off >>= 1) ss += __shfl_down(ss, off);
      if (lane == 0) red[wave] = ss;
      __syncthreads();
      const float inv = 1.f / sqrtf(red[0] + red[1] + red[2] + red[3]);
      #pragma unroll
      for (int u = 0; u < 8; ++u) rreg[u] *= inv;
      __syncthreads();                  // red[] reused next chain step
    }

    #pragma unroll
    for (int u = 0; u < 8; ++u) out_em[(size_t)y * D_ + t + u * 256] = rreg[u];
  }
}

// ---------------------------------------------------------------------------
extern "C" void kernel_launch(void* const* d_in, const int* in_sizes, int n_in,
                              void* d_out, int out_size, void* d_ws, size_t ws_size,
                              hipStream_t stream) {
  const float* inp   = (const float*)d_in[0];
  const int*   label = (const int*)d_in[1];
  const float* em    = (const float*)d_in[2];
  const int*   epoch = (const int*)d_in[3];

  float* out    = (float*)d_out;
  float* out_em = out + 1;
  float* logits = (float*)d_ws;
  bf16*  apack  = (bf16*)((char*)d_ws + WS_APACK_OFF);

  pack_a      <<<dim3(128),    dim3(256), 0, stream>>>(inp, apack, out);
  gemm_logits <<<dim3(NTILES), dim3(512), 0, stream>>>(apack, em, logits, out_em);
  tail        <<<dim3(2 * B_), dim3(256), 0, stream>>>(logits, label, inp, em,
                                                       epoch, out, out_em);
}